// Round 6
// baseline (54287.073 us; speedup 1.0000x reference)
//
#include <hip/hip_runtime.h>
#include <hip/hip_bf16.h>

// Problem dims
#define BSZ 32
#define SSZ 512
#define ISZ 512
#define HSZ 512
// ws layout (bytes)
#define XB_OFF   0ull                       // [S][64 kc][32 b][8] ushort (bf16 bits) = 16 MB
#define HEX_OFF  (16ull << 20)              // [2 dir][2 buf][64 kc][32 b][8] ushort = 128 KB
#define CTR_OFF  (HEX_OFF + (128ull << 10)) // flags: [dir] stride 2048 dwords; tab at dword 4096
#define CST_OFF  (CTR_OFF + (64ull << 10))  // [2 dir][32 p][32 b][16 j] fp32 = 128 KB (c-state)
#define XG_OFF   (32ull << 20)              // chunked x-gates: [sL][2 dir][32 p][32 b][64] fp32
// per-step xg bytes = 2*32*32*64*4 = 512 KB

typedef __attribute__((ext_vector_type(8)))  short short8;
typedef __attribute__((ext_vector_type(4)))  float f32x4;
typedef __attribute__((ext_vector_type(4)))  unsigned short us4;
typedef __attribute__((ext_vector_type(4)))  int i32x4;

__device__ __forceinline__ unsigned short f2bf(float f) {
    union { float f; unsigned u; } v; v.f = f;
    unsigned r = v.u + 0x7fffu + ((v.u >> 16) & 1u);   // RNE
    return (unsigned short)(r >> 16);
}

__device__ __forceinline__ float sigf(float x) { return 1.0f / (1.0f + __expf(-x)); }
__device__ __forceinline__ float tanhfast(float x) {
    float a = fabsf(x);
    float e = __expf(-2.0f * a);
    float t = (1.0f - e) / (1.0f + e);
    return x < 0.0f ? -t : t;
}

// X [B][S][I] fp32 -> Xb [t][kc][b][8] bf16-bits (MFMA A-fragment friendly layout)
__global__ void k_xpose(const float* __restrict__ X, unsigned short* __restrict__ Xb) {
    int idx = blockIdx.x * 256 + threadIdx.x;     // 2^21 threads total
    int i4 = idx & 127;                           // float4 index along I
    int t  = (idx >> 7) & 511;
    int b  = idx >> 16;
    float4 v = reinterpret_cast<const float4*>(X)[idx];
    us4 o = { f2bf(v.x), f2bf(v.y), f2bf(v.z), f2bf(v.w) };
    *reinterpret_cast<us4*>(Xb + (size_t)t * 16384 + (size_t)(i4 >> 1) * 256 + b * 8 + (i4 & 1) * 4) = o;
}

// Precompute x-projection gates for steps [s0, s0+C): xg[sL][dir][p][b][64] fp32.
// Block = (dir, p, tq); wave wv = gate; Tb = C/4 steps per block.
__launch_bounds__(256, 1)
__global__ void k_xproj(const float* __restrict__ Wih_f, const float* __restrict__ Wih_b,
                        const unsigned short* __restrict__ Xb, float* __restrict__ xg,
                        int s0, int Tb)
{
    const int tid = threadIdx.x;
    const int bid = blockIdx.x;          // 256 blocks
    const int dir = bid & 1;
    const int p   = (bid >> 1) & 31;
    const int tq  = bid >> 6;            // 0..3
    const int wv  = tid >> 6;            // gate index 0..3
    const int ln  = tid & 63;
    const int q   = ln >> 4;
    const int m15 = ln & 15;

    const float* Wih = dir ? Wih_b : Wih_f;

    short8 breg[16];
#pragma unroll
    for (int ks = 0; ks < 16; ++ks) {
        const float* wr = Wih + (size_t)(wv * 512 + p * 16 + m15) * 512 + ks * 32 + q * 8;
        short8 bb;
#pragma unroll
        for (int j = 0; j < 8; ++j) bb[j] = (short)f2bf(wr[j]);
        breg[ks] = bb;
    }

    for (int tt = 0; tt < Tb; ++tt) {
        int sL = tq * Tb + tt;
        int s  = s0 + sL;
        int t  = dir ? (511 - s) : s;
        const unsigned short* ab = Xb + (size_t)t * 16384;
        f32x4 acc0 = {0.f,0.f,0.f,0.f}, acc1 = {0.f,0.f,0.f,0.f};
#pragma unroll
        for (int ks = 0; ks < 16; ++ks) {
            const unsigned short* ap = ab + (ks * 4 + q) * 256 + m15 * 8;
            short8 a0 = *reinterpret_cast<const short8*>(ap);
            short8 a1 = *reinterpret_cast<const short8*>(ap + 128);
            acc0 = __builtin_amdgcn_mfma_f32_16x16x32_bf16(a0, breg[ks], acc0, 0, 0, 0);
            acc1 = __builtin_amdgcn_mfma_f32_16x16x32_bf16(a1, breg[ks], acc1, 0, 0, 0);
        }
        float* ob = xg + (((size_t)sL * 2 + dir) * 32 + p) * 2048;
#pragma unroll
        for (int r = 0; r < 4; ++r) {
            ob[(q * 4 + r) * 64      + wv * 16 + m15] = acc0[r];
            ob[(16 + q * 4 + r) * 64 + wv * 16 + m15] = acc1[r];
        }
    }
}

// Recurrence-only chunk kernel: steps [s0, s0+CL). 4 waves all do h@Whh^T, K-split.
// Wave wv waits only on its 8 K-slice producer flags.
__launch_bounds__(256, 1)
__global__ void k_bilstm2(const float* __restrict__ Whh_f, const float* __restrict__ Whh_b,
                          const float* __restrict__ bih_f, const float* __restrict__ bhh_f,
                          const float* __restrict__ bih_b, const float* __restrict__ bhh_b,
                          const float* __restrict__ xg,
                          unsigned short* h_ex, unsigned* flags, float* __restrict__ cstg_all,
                          float* __restrict__ out, int s0, int CL, int tag)
{
    const int tid = threadIdx.x;
    const int grp = blockIdx.x & 7;
    if (grp >= 2) return;                // 256 blocks: XCD0 = dir0, XCD1 = dir1
    const int dir = grp;
    const int p   = blockIdx.x >> 3;     // 0..31 : owns h-cols [16p, 16p+16)
    const int wv  = tid >> 6;            // K-slice owner
    const int ln  = tid & 63;
    const int q   = ln >> 4;
    const int m15 = ln & 15;

    unsigned* tab = flags + 4096;
    {
        unsigned xcc;
        asm volatile("s_getreg_b32 %0, hwreg(20, 0, 32)" : "=s"(xcc));
        if (tid == 0)
            __hip_atomic_store(tab + dir * 32 + p, ((unsigned)tag << 8) | ((xcc & 7u) + 1u),
                               __ATOMIC_RELAXED, __HIP_MEMORY_SCOPE_AGENT);
    }

    const float* Whh = dir ? Whh_b : Whh_f;
    const float* bi  = dir ? bih_b : bih_f;
    const float* bh  = dir ? bhh_b : bhh_f;

    __shared__ float gates[4][32][67];   // 4 K-partial planes
    __shared__ float cst[32][16];
    __shared__ float bias[64];
    __shared__ int   mode_sh;

    // weights: wave wv keeps all 4 gates for its K-slice [wv*128, +128)
    short8 breg[4][4];
#pragma unroll
    for (int ksl = 0; ksl < 4; ++ksl)
#pragma unroll
        for (int g = 0; g < 4; ++g) {
            const float* wr = Whh + (size_t)(g * 512 + p * 16 + m15) * 512
                                  + wv * 128 + ksl * 32 + q * 8;
            short8 bb;
#pragma unroll
            for (int j = 0; j < 8; ++j) bb[j] = (short)f2bf(wr[j]);
            breg[ksl][g] = bb;
        }

    if (tid < 64) {
        int c = tid;
        int gr = (c >> 4) * 512 + p * 16 + (c & 15);
        bias[c] = bi[gr] + bh[gr];
    }
    // c-state: load persisted chunk state (zeroed by memset before chunk 0)
    float* cstg = cstg_all + (size_t)(dir * 32 + p) * 512;
    for (int i = tid; i < 512; i += 256) ((float*)cst)[i] = cstg[i];

    // placement discovery, chunk-tagged (deadlock-free: every owner writes its slot)
    if (tid < 64) {
        const unsigned* tp = tab + dir * 32 + (tid & 31);
        unsigned v;
        do { v = __hip_atomic_load(tp, __ATOMIC_RELAXED, __HIP_MEMORY_SCOPE_AGENT); }
        while ((v >> 8) != (unsigned)tag);
        unsigned ref = __shfl(v, 0);
        int same = (__ballot(v == ref) == ~0ull) ? 1 : 0;
        if (tid == 0) mode_sh = same;
    }
    __syncthreads();
    const int fast = mode_sh;

    unsigned* flg = flags + (size_t)dir * 2048;
    unsigned short* hexd = h_ex + (size_t)dir * 2 * 16384;

    const int b  = tid >> 3;
    const int j0 = (tid & 7) * 2;

    int agent_poll = 0;

    for (int s = s0; s < s0 + CL; ++s) {
        const int t  = dir ? (511 - s) : s;
        const int sL = s - s0;
        const float* xgp = xg + (((size_t)sL * 2 + dir) * 32 + p) * 2048 + b * 64 + j0;

        f32x4 acc[4][2];
#pragma unroll
        for (int g = 0; g < 4; ++g) { acc[g][0] = {0.f,0.f,0.f,0.f}; acc[g][1] = {0.f,0.f,0.f,0.f}; }
        float2 xgv[4];

        if (fast) {
            if (s > 0) {
                // wave wv needs only its 8 K-slice producers: flags [wv*8, wv*8+8)
                const unsigned* fp = flg + wv * 8 + (ln & 7);
                if (!agent_poll) {
                    int spins = 0;
                    for (;;) {
                        unsigned v;
                        asm volatile("global_load_dword %0, %1, off sc0\n\t"
                                     "s_waitcnt vmcnt(0)"
                                     : "=&v"(v) : "v"(fp) : "memory");
                        if (__ballot((int)(v >= (unsigned)s)) == ~0ull) break;
                        if (++spins > 50000) { agent_poll = 1; break; }
                    }
                }
                if (agent_poll) {
                    for (;;) {
                        unsigned v = __hip_atomic_load(fp, __ATOMIC_RELAXED, __HIP_MEMORY_SCOPE_AGENT);
                        if (__ballot((int)(v >= (unsigned)s)) == ~0ull) break;
                    }
                }
                asm volatile("" ::: "memory");
            }
            // 8 h K-slice loads (sc0, L2), then 4 xg loads (cacheable)
            const unsigned short* ab = hexd + (size_t)((s + 1) & 1) * 16384 + wv * 4096;
            i32x4 A0[4], A1[4];
#pragma unroll
            for (int ksl = 0; ksl < 4; ++ksl) {
                const unsigned short* ap = ab + (ksl * 4 + q) * 256 + m15 * 8;
                asm volatile("global_load_dwordx4 %0, %2, off sc0\n\t"
                             "global_load_dwordx4 %1, %3, off sc0"
                             : "=&v"(A0[ksl]), "=&v"(A1[ksl])
                             : "v"(ap), "v"(ap + 128) : "memory");
            }
#pragma unroll
            for (int g = 0; g < 4; ++g)
                asm volatile("global_load_dwordx2 %0, %1, off"
                             : "=v"(xgv[g]) : "v"(xgp + g * 16) : "memory");
            // counted waits: 8 h-loads then 4 xg loads (vmcnt retires in issue order)
#pragma unroll
            for (int ksl = 0; ksl < 4; ++ksl) {
                asm volatile("s_waitcnt vmcnt(%0)" :: "n"(10 - 2 * ksl) : "memory");
                __builtin_amdgcn_sched_barrier(0);   // rule #18
                short8 a0 = __builtin_bit_cast(short8, A0[ksl]);
                short8 a1 = __builtin_bit_cast(short8, A1[ksl]);
#pragma unroll
                for (int g = 0; g < 4; ++g) {
                    acc[g][0] = __builtin_amdgcn_mfma_f32_16x16x32_bf16(a0, breg[ksl][g], acc[g][0], 0, 0, 0);
                    acc[g][1] = __builtin_amdgcn_mfma_f32_16x16x32_bf16(a1, breg[ksl][g], acc[g][1], 0, 0, 0);
                }
            }
        } else {
            // fallback agent/LLC path (all-32 flag wait)
            if (s > 0) {
                const unsigned* fp = flg + (ln & 31);
                for (;;) {
                    unsigned v = __hip_atomic_load(fp, __ATOMIC_RELAXED, __HIP_MEMORY_SCOPE_AGENT);
                    if (__ballot((int)(v >= (unsigned)s)) == ~0ull) break;
                }
                asm volatile("" ::: "memory");
            }
            const unsigned* abase = reinterpret_cast<const unsigned*>(
                hexd + (size_t)((s + 1) & 1) * 16384 + wv * 4096);
#pragma unroll
            for (int ksl = 0; ksl < 4; ++ksl) {
                const unsigned* ap = abase + ((ksl * 4 + q) * 256 + m15 * 8) / 2;
                union { short8 s8; unsigned u[4]; } ua0, ua1;
#pragma unroll
                for (int w = 0; w < 4; ++w) {
                    ua0.u[w] = __hip_atomic_load(ap + w,      __ATOMIC_RELAXED, __HIP_MEMORY_SCOPE_AGENT);
                    ua1.u[w] = __hip_atomic_load(ap + 64 + w, __ATOMIC_RELAXED, __HIP_MEMORY_SCOPE_AGENT);
                }
#pragma unroll
                for (int g = 0; g < 4; ++g) {
                    acc[g][0] = __builtin_amdgcn_mfma_f32_16x16x32_bf16(ua0.s8, breg[ksl][g], acc[g][0], 0, 0, 0);
                    acc[g][1] = __builtin_amdgcn_mfma_f32_16x16x32_bf16(ua1.s8, breg[ksl][g], acc[g][1], 0, 0, 0);
                }
            }
#pragma unroll
            for (int g = 0; g < 4; ++g)
                xgv[g] = *reinterpret_cast<const float2*>(xgp + g * 16);
        }

        // dump K-partial gates (plane = wv); C/D: col = ln&15, row = q*4 + r
#pragma unroll
        for (int g = 0; g < 4; ++g)
#pragma unroll
            for (int r = 0; r < 4; ++r) {
                gates[wv][q * 4 + r][g * 16 + m15]      = acc[g][0][r];
                gates[wv][16 + q * 4 + r][g * 16 + m15] = acc[g][1][r];
            }
        asm volatile("s_waitcnt lgkmcnt(0)" ::: "memory");
        __builtin_amdgcn_s_barrier();    // sync#1
        asm volatile("s_waitcnt vmcnt(0)" ::: "memory");   // xg loads landed
        __builtin_amdgcn_sched_barrier(0);                 // rule #18

        // gate math: thread (b, j0), cols j0 and j0+1
        float hv01[2], cn01[2];
        {
#pragma unroll
            for (int u = 0; u < 2; ++u) {
                int j = j0 + u;
                float ig = gates[0][b][j]      + gates[1][b][j]      + gates[2][b][j]      + gates[3][b][j]
                         + (u ? xgv[0].y : xgv[0].x) + bias[j];
                float fg = gates[0][b][16 + j] + gates[1][b][16 + j] + gates[2][b][16 + j] + gates[3][b][16 + j]
                         + (u ? xgv[1].y : xgv[1].x) + bias[16 + j];
                float gg = gates[0][b][32 + j] + gates[1][b][32 + j] + gates[2][b][32 + j] + gates[3][b][32 + j]
                         + (u ? xgv[2].y : xgv[2].x) + bias[32 + j];
                float og = gates[0][b][48 + j] + gates[1][b][48 + j] + gates[2][b][48 + j] + gates[3][b][48 + j]
                         + (u ? xgv[3].y : xgv[3].x) + bias[48 + j];
                float cn = sigf(fg) * cst[b][j] + sigf(ig) * tanhfast(gg);
                cst[b][j] = cn;
                hv01[u] = sigf(og) * tanhfast(cn);
                cn01[u] = cn;
            }
            // packed 2xbf16 h store for the next step
            int hc0 = p * 16 + j0;
            unsigned pk = (unsigned)f2bf(hv01[0]) | ((unsigned)f2bf(hv01[1]) << 16);
            unsigned* dst = reinterpret_cast<unsigned*>(
                hexd + (size_t)(s & 1) * 16384 + (size_t)(hc0 >> 3) * 256 + b * 8 + (hc0 & 7));
            if (fast) {
                asm volatile("global_store_dword %0, %1, off sc0" :: "v"(dst), "v"(pk) : "memory");
            } else {
                __hip_atomic_store(dst, pk, __ATOMIC_RELAXED, __HIP_MEMORY_SCOPE_AGENT);
            }
        }

        // publish: drain h store, barrier, flag; out stores AFTER (off the sync path)
        asm volatile("s_waitcnt vmcnt(0)" ::: "memory");
        asm volatile("s_waitcnt lgkmcnt(0)" ::: "memory");
        __builtin_amdgcn_s_barrier();    // sync#2
        if (tid == 0) {
            if (fast) {
                unsigned sv = (unsigned)(s + 1);
                asm volatile("global_store_dword %0, %1, off sc0" :: "v"(flg + p), "v"(sv) : "memory");
            } else {
                __hip_atomic_store(flg + p, (unsigned)(s + 1), __ATOMIC_RELAXED, __HIP_MEMORY_SCOPE_AGENT);
            }
        }
        {
            int hc0 = p * 16 + j0;
            *reinterpret_cast<float2*>(&out[(size_t)b * 524288 + (size_t)t * 1024
                                            + dir * 512 + hc0]) = make_float2(hv01[0], hv01[1]);
            if (s == 511) {
                *reinterpret_cast<float2*>(&out[16777216 + dir * 16384 + b * 512 + hc0])
                    = make_float2(hv01[0], hv01[1]);
                *reinterpret_cast<float2*>(&out[16777216 + 32768 + dir * 16384 + b * 512 + hc0])
                    = make_float2(cn01[0], cn01[1]);
            }
        }
    }

    // persist c-state for next chunk
    for (int i = tid; i < 512; i += 256) cstg[i] = ((float*)cst)[i];
}

// ---------------- Fallback: Round-1 kernel verbatim (used if ws too small) ----------------
__launch_bounds__(256, 1)
__global__ void k_bilstm_fb(const float* __restrict__ Wih_f, const float* __restrict__ Whh_f,
                            const float* __restrict__ bih_f, const float* __restrict__ bhh_f,
                            const float* __restrict__ Wih_b, const float* __restrict__ Whh_b,
                            const float* __restrict__ bih_b, const float* __restrict__ bhh_b,
                            const unsigned short* __restrict__ Xb,
                            unsigned short* h_ex, unsigned* flags, float* __restrict__ out)
{
    const int tid = threadIdx.x;
    const int grp = blockIdx.x & 7;
    if (grp >= 2) return;
    const int dir = grp;
    const int p   = blockIdx.x >> 3;
    const int wv  = tid >> 6;
    const int ln  = tid & 63;
    const int kh  = wv >> 1;
    const int nt  = wv & 1;
    const int q   = ln >> 4;
    const int m15 = ln & 15;

    unsigned* tab = flags + 4096;
    {
        unsigned xcc;
        asm volatile("s_getreg_b32 %0, hwreg(20, 0, 32)" : "=s"(xcc));
        if (tid == 0)
            __hip_atomic_store(tab + dir * 32 + p, (xcc & 7u) + 1u,
                               __ATOMIC_RELAXED, __HIP_MEMORY_SCOPE_AGENT);
    }

    const float* Wsel = kh ? (dir ? Whh_b : Whh_f) : (dir ? Wih_b : Wih_f);
    const float* bi   = dir ? bih_b : bih_f;
    const float* bh   = dir ? bhh_b : bhh_f;

    __shared__ float gates[2][32][67];
    __shared__ float cst[32][16];
    __shared__ float bias[64];
    __shared__ int   mode_sh;

    short8 breg[16][2];
    {
        const float* wr0 = Wsel + (size_t)((nt * 2 + 0) * 512 + p * 16 + m15) * 512 + q * 8;
        const float* wr1 = Wsel + (size_t)((nt * 2 + 1) * 512 + p * 16 + m15) * 512 + q * 8;
#pragma unroll
        for (int ks = 0; ks < 16; ++ks) {
            short8 b0, b1;
#pragma unroll
            for (int j = 0; j < 8; ++j) {
                b0[j] = (short)f2bf(wr0[ks * 32 + j]);
                b1[j] = (short)f2bf(wr1[ks * 32 + j]);
            }
            breg[ks][0] = b0; breg[ks][1] = b1;
        }
    }

    if (tid < 64) {
        int c = tid;
        int gr = (c >> 4) * 512 + p * 16 + (c & 15);
        bias[c] = bi[gr] + bh[gr];
    }
    for (int i = tid; i < 512; i += 256) ((float*)cst)[i] = 0.0f;

    if (tid < 64) {
        const unsigned* tp = tab + dir * 32 + (tid & 31);
        unsigned v;
        do { v = __hip_atomic_load(tp, __ATOMIC_RELAXED, __HIP_MEMORY_SCOPE_AGENT); } while (v == 0u);
        unsigned ref = __shfl(v, 0);
        int same = (__ballot(v == ref) == ~0ull) ? 1 : 0;
        if (tid == 0) mode_sh = same;
    }
    __syncthreads();
    const int fast = mode_sh;

    unsigned* flg = flags + (size_t)dir * 2048;
    unsigned short* hexd = h_ex + (size_t)dir * 2 * 16384;

    int agent_poll = 0;

    for (int s = 0; s < 512; ++s) {
        const int t = dir ? (511 - s) : s;
        f32x4 acc00 = {0.f,0.f,0.f,0.f}, acc01 = {0.f,0.f,0.f,0.f};
        f32x4 acc10 = {0.f,0.f,0.f,0.f}, acc11 = {0.f,0.f,0.f,0.f};

        if (kh == 0) {
            const unsigned short* abase = Xb + (size_t)t * 16384;
#pragma unroll
            for (int ks = 0; ks < 16; ++ks) {
                const unsigned short* ap = abase + (size_t)(ks * 4 + q) * 256 + m15 * 8;
                short8 a0 = *reinterpret_cast<const short8*>(ap);
                short8 a1 = *reinterpret_cast<const short8*>(ap + 128);
                acc00 = __builtin_amdgcn_mfma_f32_16x16x32_bf16(a0, breg[ks][0], acc00, 0, 0, 0);
                acc01 = __builtin_amdgcn_mfma_f32_16x16x32_bf16(a0, breg[ks][1], acc01, 0, 0, 0);
                acc10 = __builtin_amdgcn_mfma_f32_16x16x32_bf16(a1, breg[ks][0], acc10, 0, 0, 0);
                acc11 = __builtin_amdgcn_mfma_f32_16x16x32_bf16(a1, breg[ks][1], acc11, 0, 0, 0);
            }
        } else if (fast) {
            if (s > 0) {
                const unsigned* fp = flg + (ln & 31);
                if (!agent_poll) {
                    int spins = 0;
                    for (;;) {
                        unsigned v;
                        asm volatile("global_load_dword %0, %1, off sc0\n\t"
                                     "s_waitcnt vmcnt(0)"
                                     : "=&v"(v) : "v"(fp) : "memory");
                        if (__ballot((int)(v >= (unsigned)s)) == ~0ull) break;
                        if (++spins > 20000) { agent_poll = 1; break; }
                    }
                }
                if (agent_poll) {
                    for (;;) {
                        unsigned v = __hip_atomic_load(fp, __ATOMIC_RELAXED, __HIP_MEMORY_SCOPE_AGENT);
                        if (__ballot((int)(v >= (unsigned)s)) == ~0ull) break;
                    }
                }
                asm volatile("" ::: "memory");
            }
            const unsigned short* ab = hexd + (size_t)((s + 1) & 1) * 16384;
            i32x4 A0[16], A1[16];
#pragma unroll
            for (int ks = 0; ks < 16; ++ks) {
                const unsigned short* ap = ab + (size_t)(ks * 4 + q) * 256 + m15 * 8;
                asm volatile("global_load_dwordx4 %0, %2, off sc0\n\t"
                             "global_load_dwordx4 %1, %3, off sc0"
                             : "=&v"(A0[ks]), "=&v"(A1[ks])
                             : "v"(ap), "v"(ap + 128) : "memory");
            }
#pragma unroll
            for (int ks = 0; ks < 16; ++ks) {
                asm volatile("s_waitcnt vmcnt(%0)" :: "n"(30 - 2 * ks) : "memory");
                __builtin_amdgcn_sched_barrier(0);
                short8 a0 = __builtin_bit_cast(short8, A0[ks]);
                short8 a1 = __builtin_bit_cast(short8, A1[ks]);
                acc00 = __builtin_amdgcn_mfma_f32_16x16x32_bf16(a0, breg[ks][0], acc00, 0, 0, 0);
                acc01 = __builtin_amdgcn_mfma_f32_16x16x32_bf16(a0, breg[ks][1], acc01, 0, 0, 0);
                acc10 = __builtin_amdgcn_mfma_f32_16x16x32_bf16(a1, breg[ks][0], acc10, 0, 0, 0);
                acc11 = __builtin_amdgcn_mfma_f32_16x16x32_bf16(a1, breg[ks][1], acc11, 0, 0, 0);
            }
        } else {
            if (s > 0) {
                const unsigned* fp = flg + (ln & 31);
                for (;;) {
                    unsigned v = __hip_atomic_load(fp, __ATOMIC_RELAXED, __HIP_MEMORY_SCOPE_AGENT);
                    if (__ballot((int)(v >= (unsigned)s)) == ~0ull) break;
                }
                asm volatile("" ::: "memory");
            }
            const unsigned* abase = reinterpret_cast<const unsigned*>(hexd + (size_t)((s + 1) & 1) * 16384);
#pragma unroll
            for (int ks = 0; ks < 16; ++ks) {
                const unsigned* ap = abase + ((ks * 4 + q) * 256 + m15 * 8) / 2;
                union { short8 s8; unsigned u[4]; } ua0, ua1;
#pragma unroll
                for (int w = 0; w < 4; ++w) {
                    ua0.u[w] = __hip_atomic_load(ap + w,      __ATOMIC_RELAXED, __HIP_MEMORY_SCOPE_AGENT);
                    ua1.u[w] = __hip_atomic_load(ap + 64 + w, __ATOMIC_RELAXED, __HIP_MEMORY_SCOPE_AGENT);
                }
                acc00 = __builtin_amdgcn_mfma_f32_16x16x32_bf16(ua0.s8, breg[ks][0], acc00, 0, 0, 0);
                acc01 = __builtin_amdgcn_mfma_f32_16x16x32_bf16(ua0.s8, breg[ks][1], acc01, 0, 0, 0);
                acc10 = __builtin_amdgcn_mfma_f32_16x16x32_bf16(ua1.s8, breg[ks][0], acc10, 0, 0, 0);
                acc11 = __builtin_amdgcn_mfma_f32_16x16x32_bf16(ua1.s8, breg[ks][1], acc11, 0, 0, 0);
            }
        }

        {
            int rb = q * 4;
            int cb = nt * 32 + m15;
#pragma unroll
            for (int r = 0; r < 4; ++r) {
                gates[kh][rb + r][cb]           = acc00[r];
                gates[kh][rb + r][cb + 16]      = acc01[r];
                gates[kh][16 + rb + r][cb]      = acc10[r];
                gates[kh][16 + rb + r][cb + 16] = acc11[r];
            }
        }
        __syncthreads();

        int b  = tid >> 3;
        int j0 = (tid & 7) * 2;
        float hv01[2], cn01[2];
        {
#pragma unroll
            for (int u = 0; u < 2; ++u) {
                int j = j0 + u;
                float ig = gates[0][b][j]      + gates[1][b][j]      + bias[j];
                float fg = gates[0][b][16 + j] + gates[1][b][16 + j] + bias[16 + j];
                float gg = gates[0][b][32 + j] + gates[1][b][32 + j] + bias[32 + j];
                float og = gates[0][b][48 + j] + gates[1][b][48 + j] + bias[48 + j];
                float cn = sigf(fg) * cst[b][j] + sigf(ig) * tanhfast(gg);
                cst[b][j] = cn;
                float hv = sigf(og) * tanhfast(cn);
                hv01[u] = hv; cn01[u] = cn;
            }
            int hc0 = p * 16 + j0;
            unsigned pk = (unsigned)f2bf(hv01[0]) | ((unsigned)f2bf(hv01[1]) << 16);
            unsigned* dst = reinterpret_cast<unsigned*>(
                hexd + (size_t)(s & 1) * 16384 + (size_t)(hc0 >> 3) * 256 + b * 8 + (hc0 & 7));
            if (fast) {
                asm volatile("global_store_dword %0, %1, off sc0" :: "v"(dst), "v"(pk) : "memory");
            } else {
                __hip_atomic_store(dst, pk, __ATOMIC_RELAXED, __HIP_MEMORY_SCOPE_AGENT);
            }
        }

        asm volatile("s_waitcnt vmcnt(0)" ::: "memory");
        __syncthreads();
        if (tid == 0) {
            if (fast) {
                unsigned sv = (unsigned)(s + 1);
                asm volatile("global_store_dword %0, %1, off sc0" :: "v"(flg + p), "v"(sv) : "memory");
            } else {
                __hip_atomic_store(flg + p, (unsigned)(s + 1), __ATOMIC_RELAXED, __HIP_MEMORY_SCOPE_AGENT);
            }
        }

#pragma unroll
        for (int u = 0; u < 2; ++u) {
            int hc = p * 16 + j0 + u;
            out[(size_t)b * (512 * 1024) + (size_t)t * 1024 + dir * 512 + hc] = hv01[u];
            if (s == 511) {
                out[16777216 + dir * 16384 + b * 512 + hc] = hv01[u];
                out[16777216 + 32768 + dir * 16384 + b * 512 + hc] = cn01[u];
            }
        }
    }
}

extern "C" void kernel_launch(void* const* d_in, const int* in_sizes, int n_in,
                              void* d_out, int out_size, void* d_ws, size_t ws_size,
                              hipStream_t stream) {
    const float* X     = (const float*)d_in[0];
    const float* Wih_f = (const float*)d_in[1];
    const float* Whh_f = (const float*)d_in[2];
    const float* bih_f = (const float*)d_in[3];
    const float* bhh_f = (const float*)d_in[4];
    const float* Wih_b = (const float*)d_in[5];
    const float* Whh_b = (const float*)d_in[6];
    const float* bih_b = (const float*)d_in[7];
    const float* bhh_b = (const float*)d_in[8];
    float* out = (float*)d_out;

    unsigned short* Xb   = (unsigned short*)((char*)d_ws + XB_OFF);
    unsigned short* h_ex = (unsigned short*)((char*)d_ws + HEX_OFF);
    unsigned*       flg  = (unsigned*)((char*)d_ws + CTR_OFF);
    float*          cstg = (float*)((char*)d_ws + CST_OFF);
    float*          xg   = (float*)((char*)d_ws + XG_OFF);

    // zero h_ex (h_{-1}=0) + flags + placement table + c-state
    hipMemsetAsync((char*)d_ws + HEX_OFF, 0, (128ull + 64ull + 128ull) << 10, stream);
    k_xpose<<<8192, 256, 0, stream>>>(X, Xb);

    // choose time-chunk size from available workspace (512 KB of xg per step)
    const size_t per_step = 2ull * 32 * 32 * 64 * 4;
    int C = 0;
    for (int cand = 512; cand >= 32; cand >>= 1)
        if (ws_size >= XG_OFF + (size_t)cand * per_step) { C = cand; break; }

    if (C > 0) {
        const int nchunks = 512 / C;
        for (int c = 0; c < nchunks; ++c) {
            k_xproj<<<256, 256, 0, stream>>>(Wih_f, Wih_b, Xb, xg, c * C, C / 4);
            k_bilstm2<<<256, 256, 0, stream>>>(Whh_f, Whh_b, bih_f, bhh_f, bih_b, bhh_b,
                                               xg, h_ex, flg, cstg, out, c * C, C, c + 1);
        }
    } else {
        k_bilstm_fb<<<256, 256, 0, stream>>>(Wih_f, Whh_f, bih_f, bhh_f,
                                             Wih_b, Whh_b, bih_b, bhh_b,
                                             Xb, h_ex, flg, out);
    }
}

// Round 7
// 4286.881 us; speedup vs baseline: 12.6635x; 12.6635x over previous
//
#include <hip/hip_runtime.h>
#include <hip/hip_bf16.h>

// Problem dims
#define BSZ 32
#define SSZ 512
#define ISZ 512
#define HSZ 512
// ws layout (bytes)
#define XB_OFF   0ull                       // [S][64 kc][32 b][8] ushort (bf16 bits) = 16 MB
#define HEX_OFF  (16ull << 20)              // [2 dir][2 buf][64 kc][32 b][8] ushort = 128 KB
#define CTR_OFF  (HEX_OFF + (128ull << 10)) // flags: [dir] stride 2048 dwords; tab at dword 4096

typedef __attribute__((ext_vector_type(8)))  short short8;
typedef __attribute__((ext_vector_type(4)))  float f32x4;
typedef __attribute__((ext_vector_type(4)))  unsigned short us4;
typedef __attribute__((ext_vector_type(4)))  int i32x4;

__device__ __forceinline__ unsigned short f2bf(float f) {
    union { float f; unsigned u; } v; v.f = f;
    unsigned r = v.u + 0x7fffu + ((v.u >> 16) & 1u);   // RNE
    return (unsigned short)(r >> 16);
}

__device__ __forceinline__ float sigf(float x) { return 1.0f / (1.0f + __expf(-x)); }
__device__ __forceinline__ float tanhfast(float x) {
    float a = fabsf(x);
    float e = __expf(-2.0f * a);
    float t = (1.0f - e) / (1.0f + e);
    return x < 0.0f ? -t : t;
}

// X [B][S][I] fp32 -> Xb [t][kc][b][8] bf16-bits (MFMA A-fragment friendly layout)
__global__ void k_xpose(const float* __restrict__ X, unsigned short* __restrict__ Xb) {
    int idx = blockIdx.x * 256 + threadIdx.x;     // 2^21 threads total
    int i4 = idx & 127;                           // float4 index along I
    int t  = (idx >> 7) & 511;
    int b  = idx >> 16;
    float4 v = reinterpret_cast<const float4*>(X)[idx];
    us4 o = { f2bf(v.x), f2bf(v.y), f2bf(v.z), f2bf(v.w) };
    *reinterpret_cast<us4*>(Xb + (size_t)t * 16384 + (size_t)(i4 >> 1) * 256 + b * 8 + (i4 & 1) * 4) = o;
}

// R1 structure. ONE change: out/stacked stores are deferred to the x-waves via an
// LDS outbuf, so the h-waves' vmem stream contains ONLY {poll loads, h loads, h store}
// and their per-step poll vmcnt(0) never drains an HBM store ack.
__launch_bounds__(256, 1)
__global__ void k_bilstm(const float* __restrict__ Wih_f, const float* __restrict__ Whh_f,
                         const float* __restrict__ bih_f, const float* __restrict__ bhh_f,
                         const float* __restrict__ Wih_b, const float* __restrict__ Whh_b,
                         const float* __restrict__ bih_b, const float* __restrict__ bhh_b,
                         const unsigned short* __restrict__ Xb,
                         unsigned short* h_ex, unsigned* flags, float* __restrict__ out)
{
    const int tid = threadIdx.x;
    const int grp = blockIdx.x & 7;
    if (grp >= 2) return;                // 256 blocks: XCD0 = dir0, XCD1 = dir1
    const int dir = grp;
    const int p   = blockIdx.x >> 3;     // 0..31 : owns h-cols [16p, 16p+16)
    const int wv  = tid >> 6;
    const int ln  = tid & 63;
    const int kh  = wv >> 1;             // 0: x-projection, 1: h-recurrence
    const int nt  = wv & 1;              // gate-pair tile (0: i,f ; 1: g,o)
    const int q   = ln >> 4;
    const int m15 = ln & 15;

    unsigned* tab = flags + 4096;
    {
        unsigned xcc;
        asm volatile("s_getreg_b32 %0, hwreg(20, 0, 32)" : "=s"(xcc));
        if (tid == 0)
            __hip_atomic_store(tab + dir * 32 + p, (xcc & 7u) + 1u,
                               __ATOMIC_RELAXED, __HIP_MEMORY_SCOPE_AGENT);
    }

    const float* Wsel = kh ? (dir ? Whh_b : Whh_f) : (dir ? Wih_b : Wih_f);
    const float* bi   = dir ? bih_b : bih_f;
    const float* bh   = dir ? bhh_b : bhh_f;

    __shared__ float gates[2][32][67];   // 67: breaks even-bank 4-way conflicts
    __shared__ float cst[32][16];
    __shared__ float outbuf[2][32][16];  // h (fp32) bounce: gate math -> x-wave stores
    __shared__ float bias[64];
    __shared__ int   mode_sh;

    // ---- load B fragments (weights) into registers, kept for all 512 steps ----
    short8 breg[16][2];
    {
        const float* wr0 = Wsel + (size_t)((nt * 2 + 0) * 512 + p * 16 + m15) * 512 + q * 8;
        const float* wr1 = Wsel + (size_t)((nt * 2 + 1) * 512 + p * 16 + m15) * 512 + q * 8;
#pragma unroll
        for (int ks = 0; ks < 16; ++ks) {
            short8 b0, b1;
#pragma unroll
            for (int j = 0; j < 8; ++j) {
                b0[j] = (short)f2bf(wr0[ks * 32 + j]);
                b1[j] = (short)f2bf(wr1[ks * 32 + j]);
            }
            breg[ks][0] = b0; breg[ks][1] = b1;
        }
    }

    if (tid < 64) {
        int c = tid;
        int gr = (c >> 4) * 512 + p * 16 + (c & 15);
        bias[c] = bi[gr] + bh[gr];
    }
    for (int i = tid; i < 512; i += 256) ((float*)cst)[i] = 0.0f;

    // ---- placement discovery (deadlock-free: every owner writes its slot) ----
    if (tid < 64) {
        const unsigned* tp = tab + dir * 32 + (tid & 31);
        unsigned v;
        do { v = __hip_atomic_load(tp, __ATOMIC_RELAXED, __HIP_MEMORY_SCOPE_AGENT); } while (v == 0u);
        unsigned ref = __shfl(v, 0);
        int same = (__ballot(v == ref) == ~0ull) ? 1 : 0;
        if (tid == 0) mode_sh = same;
    }
    __syncthreads();
    const int fast = mode_sh;

    unsigned* flg = flags + (size_t)dir * 2048;
    unsigned short* hexd = h_ex + (size_t)dir * 2 * 16384;

    int agent_poll = 0;

    for (int s = 0; s < 512; ++s) {
        const int t = dir ? (511 - s) : s;
        f32x4 acc00 = {0.f,0.f,0.f,0.f}, acc01 = {0.f,0.f,0.f,0.f};
        f32x4 acc10 = {0.f,0.f,0.f,0.f}, acc11 = {0.f,0.f,0.f,0.f};

        if (kh == 0) {
            // ---- deferred out stores for step s-1 (x-waves only; acks hide under GEMM) ----
            if (s > 0) {
                int pt = dir ? (512 - s) : (s - 1);
                int b  = tid >> 2;           // tid in [0,128): b = tid>>2, qd = tid&3
                int qd = tid & 3;
                f32x4 hvv = *reinterpret_cast<const f32x4*>(&outbuf[(s - 1) & 1][b][qd * 4]);
                *reinterpret_cast<f32x4*>(&out[(size_t)b * 524288 + (size_t)pt * 1024
                                               + dir * 512 + p * 16 + qd * 4]) = hvv;
            }
            // ---- x-projection GEMM (plain L2-cacheable loads, as R1) ----
            const unsigned short* abase = Xb + (size_t)t * 16384;
#pragma unroll
            for (int ks = 0; ks < 16; ++ks) {
                const unsigned short* ap = abase + (size_t)(ks * 4 + q) * 256 + m15 * 8;
                short8 a0 = *reinterpret_cast<const short8*>(ap);
                short8 a1 = *reinterpret_cast<const short8*>(ap + 128);
                acc00 = __builtin_amdgcn_mfma_f32_16x16x32_bf16(a0, breg[ks][0], acc00, 0, 0, 0);
                acc01 = __builtin_amdgcn_mfma_f32_16x16x32_bf16(a0, breg[ks][1], acc01, 0, 0, 0);
                acc10 = __builtin_amdgcn_mfma_f32_16x16x32_bf16(a1, breg[ks][0], acc10, 0, 0, 0);
                acc11 = __builtin_amdgcn_mfma_f32_16x16x32_bf16(a1, breg[ks][1], acc11, 0, 0, 0);
            }
        } else if (fast) {
            // ---- h-recurrence, XCD-local L2 path (vmem stream: poll + h loads only) ----
            if (s > 0) {
                const unsigned* fp = flg + (ln & 31);
                if (!agent_poll) {
                    int spins = 0;
                    for (;;) {
                        unsigned v;
                        asm volatile("global_load_dword %0, %1, off sc0\n\t"
                                     "s_waitcnt vmcnt(0)"
                                     : "=&v"(v) : "v"(fp) : "memory");
                        if (__ballot((int)(v >= (unsigned)s)) == ~0ull) break;
                        if (++spins > 20000) { agent_poll = 1; break; }
                    }
                }
                if (agent_poll) {
                    for (;;) {
                        unsigned v = __hip_atomic_load(fp, __ATOMIC_RELAXED, __HIP_MEMORY_SCOPE_AGENT);
                        if (__ballot((int)(v >= (unsigned)s)) == ~0ull) break;
                    }
                }
                asm volatile("" ::: "memory");
            }
            const unsigned short* ab = hexd + (size_t)((s + 1) & 1) * 16384;
            i32x4 A0[16], A1[16];
#pragma unroll
            for (int ks = 0; ks < 16; ++ks) {
                const unsigned short* ap = ab + (size_t)(ks * 4 + q) * 256 + m15 * 8;
                asm volatile("global_load_dwordx4 %0, %2, off sc0\n\t"
                             "global_load_dwordx4 %1, %3, off sc0"
                             : "=&v"(A0[ks]), "=&v"(A1[ks])
                             : "v"(ap), "v"(ap + 128) : "memory");
            }
#pragma unroll
            for (int ks = 0; ks < 16; ++ks) {
                asm volatile("s_waitcnt vmcnt(%0)" :: "n"(30 - 2 * ks) : "memory");
                __builtin_amdgcn_sched_barrier(0);
                short8 a0 = __builtin_bit_cast(short8, A0[ks]);
                short8 a1 = __builtin_bit_cast(short8, A1[ks]);
                acc00 = __builtin_amdgcn_mfma_f32_16x16x32_bf16(a0, breg[ks][0], acc00, 0, 0, 0);
                acc01 = __builtin_amdgcn_mfma_f32_16x16x32_bf16(a0, breg[ks][1], acc01, 0, 0, 0);
                acc10 = __builtin_amdgcn_mfma_f32_16x16x32_bf16(a1, breg[ks][0], acc10, 0, 0, 0);
                acc11 = __builtin_amdgcn_mfma_f32_16x16x32_bf16(a1, breg[ks][1], acc11, 0, 0, 0);
            }
        } else {
            // ---- h-recurrence, fallback agent/LLC path ----
            if (s > 0) {
                const unsigned* fp = flg + (ln & 31);
                for (;;) {
                    unsigned v = __hip_atomic_load(fp, __ATOMIC_RELAXED, __HIP_MEMORY_SCOPE_AGENT);
                    if (__ballot((int)(v >= (unsigned)s)) == ~0ull) break;
                }
                asm volatile("" ::: "memory");
            }
            const unsigned* abase = reinterpret_cast<const unsigned*>(hexd + (size_t)((s + 1) & 1) * 16384);
#pragma unroll
            for (int ks = 0; ks < 16; ++ks) {
                const unsigned* ap = abase + ((ks * 4 + q) * 256 + m15 * 8) / 2;
                union { short8 s8; unsigned u[4]; } ua0, ua1;
#pragma unroll
                for (int w = 0; w < 4; ++w) {
                    ua0.u[w] = __hip_atomic_load(ap + w,      __ATOMIC_RELAXED, __HIP_MEMORY_SCOPE_AGENT);
                    ua1.u[w] = __hip_atomic_load(ap + 64 + w, __ATOMIC_RELAXED, __HIP_MEMORY_SCOPE_AGENT);
                }
                acc00 = __builtin_amdgcn_mfma_f32_16x16x32_bf16(ua0.s8, breg[ks][0], acc00, 0, 0, 0);
                acc01 = __builtin_amdgcn_mfma_f32_16x16x32_bf16(ua0.s8, breg[ks][1], acc01, 0, 0, 0);
                acc10 = __builtin_amdgcn_mfma_f32_16x16x32_bf16(ua1.s8, breg[ks][0], acc10, 0, 0, 0);
                acc11 = __builtin_amdgcn_mfma_f32_16x16x32_bf16(ua1.s8, breg[ks][1], acc11, 0, 0, 0);
            }
        }

        // ---- dump partial gates to LDS (C/D layout: col = ln&15, row = q*4 + r) ----
        {
            int rb = q * 4;
            int cb = nt * 32 + m15;
#pragma unroll
            for (int r = 0; r < 4; ++r) {
                gates[kh][rb + r][cb]           = acc00[r];
                gates[kh][rb + r][cb + 16]      = acc01[r];
                gates[kh][16 + rb + r][cb]      = acc10[r];
                gates[kh][16 + rb + r][cb + 16] = acc11[r];
            }
        }
        __syncthreads();   // sync#1: both dumps visible

        // ---- gate math: each thread handles (b, j0) and (b, j0+1) ----
        {
            int b  = tid >> 3;
            int j0 = (tid & 7) * 2;
            float hv01[2];
#pragma unroll
            for (int u = 0; u < 2; ++u) {
                int j = j0 + u;
                float ig = gates[0][b][j]      + gates[1][b][j]      + bias[j];
                float fg = gates[0][b][16 + j] + gates[1][b][16 + j] + bias[16 + j];
                float gg = gates[0][b][32 + j] + gates[1][b][32 + j] + bias[32 + j];
                float og = gates[0][b][48 + j] + gates[1][b][48 + j] + bias[48 + j];
                float cn = sigf(fg) * cst[b][j] + sigf(ig) * tanhfast(gg);
                cst[b][j] = cn;
                hv01[u] = sigf(og) * tanhfast(cn);
            }
            *reinterpret_cast<float2*>(&outbuf[s & 1][b][j0]) = make_float2(hv01[0], hv01[1]);
            // packed 2xbf16 h store for the next step (the ONLY global store this phase)
            int hc0 = p * 16 + j0;
            unsigned pk = (unsigned)f2bf(hv01[0]) | ((unsigned)f2bf(hv01[1]) << 16);
            unsigned* dst = reinterpret_cast<unsigned*>(
                hexd + (size_t)(s & 1) * 16384 + (size_t)(hc0 >> 3) * 256 + b * 8 + (hc0 & 7));
            if (fast) {
                asm volatile("global_store_dword %0, %1, off sc0" :: "v"(dst), "v"(pk) : "memory");
            } else {
                __hip_atomic_store(dst, pk, __ATOMIC_RELAXED, __HIP_MEMORY_SCOPE_AGENT);
            }
        }

        // ---- publish: drain h stores, block barrier, single flag STORE ----
        asm volatile("s_waitcnt vmcnt(0)" ::: "memory");
        __syncthreads();   // sync#2: all waves' h stores acked; gates/outbuf safe to reuse
        if (tid == 0) {
            if (fast) {
                unsigned sv = (unsigned)(s + 1);
                asm volatile("global_store_dword %0, %1, off sc0" :: "v"(flg + p), "v"(sv) : "memory");
            } else {
                __hip_atomic_store(flg + p, (unsigned)(s + 1), __ATOMIC_RELAXED, __HIP_MEMORY_SCOPE_AGENT);
            }
        }
    }

    // ---- epilogue: step-511 out + final states (x-waves, 128 lanes) ----
    if (kh == 0) {
        int b  = tid >> 2;
        int qd = tid & 3;
        int tl = dir ? 0 : 511;
        f32x4 hvv = *reinterpret_cast<const f32x4*>(&outbuf[1][b][qd * 4]);   // s=511 parity
        *reinterpret_cast<f32x4*>(&out[(size_t)b * 524288 + (size_t)tl * 1024
                                       + dir * 512 + p * 16 + qd * 4]) = hvv;
        *reinterpret_cast<f32x4*>(&out[16777216 + dir * 16384 + b * 512 + p * 16 + qd * 4]) = hvv;
        f32x4 cvv = *reinterpret_cast<const f32x4*>(&cst[b][qd * 4]);
        *reinterpret_cast<f32x4*>(&out[16777216 + 32768 + dir * 16384 + b * 512 + p * 16 + qd * 4]) = cvv;
    }
}

extern "C" void kernel_launch(void* const* d_in, const int* in_sizes, int n_in,
                              void* d_out, int out_size, void* d_ws, size_t ws_size,
                              hipStream_t stream) {
    const float* X     = (const float*)d_in[0];
    const float* Wih_f = (const float*)d_in[1];
    const float* Whh_f = (const float*)d_in[2];
    const float* bih_f = (const float*)d_in[3];
    const float* bhh_f = (const float*)d_in[4];
    const float* Wih_b = (const float*)d_in[5];
    const float* Whh_b = (const float*)d_in[6];
    const float* bih_b = (const float*)d_in[7];
    const float* bhh_b = (const float*)d_in[8];
    float* out = (float*)d_out;

    unsigned short* Xb   = (unsigned short*)((char*)d_ws + XB_OFF);
    unsigned short* h_ex = (unsigned short*)((char*)d_ws + HEX_OFF);
    unsigned*       flg  = (unsigned*)((char*)d_ws + CTR_OFF);

    // zero h_ex (h_{-1}=0) + flags + placement table
    hipMemsetAsync((char*)d_ws + HEX_OFF, 0, (128ull + 64ull) << 10, stream);
    k_xpose<<<8192, 256, 0, stream>>>(X, Xb);
    // 256 blocks (1/CU): round-robin puts (blockIdx&7)==d on XCD d.
    k_bilstm<<<256, 256, 0, stream>>>(Wih_f, Whh_f, bih_f, bhh_f,
                                      Wih_b, Whh_b, bih_b, bhh_b,
                                      Xb, h_ex, flg, out);
}